// Round 1
// baseline (1547.294 us; speedup 1.0000x reference)
//
#include <hip/hip_runtime.h>
#include <hip/hip_bf16.h>

#define N_NODES 50000
#define N_EDGES 640000
#define N_GRAPHS 64
#define IN_FEAT 8
#define H 128
#define H2 256
#define NCLS 4
#define NL 6
#define EPS_MSG 1e-7f
#define LN_EPS 1e-5f

// ---------------- encoder: h = x @ enc_w + enc_b ----------------
__global__ __launch_bounds__(256) void enc_kernel(
    const float* __restrict__ x, const float* __restrict__ w,
    const float* __restrict__ b, float* __restrict__ h) {
  int idx = blockIdx.x * blockDim.x + threadIdx.x;  // node*H + c
  if (idx >= N_NODES * H) return;
  int n = idx >> 7, c = idx & (H - 1);
  const float* xr = x + n * IN_FEAT;
  float acc = b[c];
#pragma unroll
  for (int k = 0; k < IN_FEAT; k++) acc += xr[k] * w[k * H + c];
  h[idx] = acc;
}

// ---------------- CSR build ----------------
__global__ __launch_bounds__(256) void hist_kernel(const int* __restrict__ dst,
                                                   int* __restrict__ cnt) {
  int e = blockIdx.x * blockDim.x + threadIdx.x;
  if (e < N_EDGES) atomicAdd(&cnt[dst[e]], 1);
}

__global__ __launch_bounds__(1024) void scan_kernel(const int* __restrict__ cnt,
                                                    int* __restrict__ rowptr) {
  __shared__ int wsum[16];
  __shared__ int s_carry;
  int tid = threadIdx.x, lane = tid & 63, w = tid >> 6;
  if (tid == 0) { s_carry = 0; rowptr[0] = 0; }
  __syncthreads();
  for (int base = 0; base < N_NODES; base += 1024) {
    int i = base + tid;
    int v = (i < N_NODES) ? cnt[i] : 0;
    int x = v;
#pragma unroll
    for (int off = 1; off < 64; off <<= 1) {
      int y = __shfl_up(x, off, 64);
      if (lane >= off) x += y;
    }
    if (lane == 63) wsum[w] = x;
    __syncthreads();
    if (w == 0 && lane < 16) {
      int ws = wsum[lane];
#pragma unroll
      for (int off = 1; off < 16; off <<= 1) {
        int y = __shfl_up(ws, off, 64);
        if (lane >= off) ws += y;
      }
      wsum[lane] = ws;  // inclusive scan of wave sums
    }
    __syncthreads();
    int waveoff = (w == 0) ? 0 : wsum[w - 1];
    int incl = s_carry + waveoff + x;
    if (i < N_NODES) rowptr[i + 1] = incl;
    __syncthreads();
    if (tid == 1023) s_carry = incl;  // lane1023 incl == chunk total + old carry
    __syncthreads();
  }
}

__global__ __launch_bounds__(256) void scatter_kernel(
    const int* __restrict__ src, const int* __restrict__ dst,
    const int* __restrict__ rowptr, int* __restrict__ cursor,
    int* __restrict__ csr) {
  int e = blockIdx.x * blockDim.x + threadIdx.x;
  if (e < N_EDGES) {
    int d = dst[e];
    int pos = rowptr[d] + atomicAdd(&cursor[d], 1);
    csr[pos] = src[e];
  }
}

// ---------------- per-layer: z = relu(LN(h)) ----------------
__global__ __launch_bounds__(256) void ln_relu_kernel(
    const float* __restrict__ h, const float* __restrict__ g,
    const float* __restrict__ b, float* __restrict__ z) {
  int node = (blockIdx.x * blockDim.x + threadIdx.x) >> 6;
  int lane = threadIdx.x & 63;
  if (node >= N_NODES) return;
  const float* hr = h + node * H;
  float v0 = hr[lane], v1 = hr[lane + 64];
  float s = v0 + v1;
#pragma unroll
  for (int off = 32; off; off >>= 1) s += __shfl_xor(s, off, 64);
  float mu = s * (1.0f / H);
  float d0 = v0 - mu, d1 = v1 - mu;
  float q = d0 * d0 + d1 * d1;
#pragma unroll
  for (int off = 32; off; off >>= 1) q += __shfl_xor(q, off, 64);
  float rstd = rsqrtf(q * (1.0f / H) + LN_EPS);
  float z0 = g[lane] * d0 * rstd + b[lane];
  float z1 = g[lane + 64] * d1 * rstd + b[lane + 64];
  z[node * H + lane] = fmaxf(z0, 0.f);
  z[node * H + lane + 64] = fmaxf(z1, 0.f);
}

// ------------- softmax aggregation: out = agg + z -------------
// agg[v] = sum_e(m*e)/sum_e(e), e = exp(m*t), m = z[src]+eps  (z >= 0)
// max-shift dropped: z bounded by sqrt(127) => exp <= ~8e4, safe in fp32;
// the shift cancels exactly in the ratio.
__global__ __launch_bounds__(256) void agg_kernel(
    const float* __restrict__ z, const int* __restrict__ rowptr,
    const int* __restrict__ csr, const float* __restrict__ tptr,
    float* __restrict__ out) {
  int v = (blockIdx.x * blockDim.x + threadIdx.x) >> 6;
  int lane = threadIdx.x & 63;
  if (v >= N_NODES) return;
  float t = *tptr;
  int beg = rowptr[v], end = rowptr[v + 1];
  float se0 = 0.f, sm0 = 0.f, se1 = 0.f, sm1 = 0.f;
  for (int e = beg; e < end; e++) {
    int s = csr[e];
    float m0 = z[s * H + lane] + EPS_MSG;
    float m1 = z[s * H + lane + 64] + EPS_MSG;
    float e0 = __expf(m0 * t), e1 = __expf(m1 * t);
    se0 += e0; sm0 += m0 * e0;
    se1 += e1; sm1 += m1 * e1;
  }
  float a0 = (end > beg) ? sm0 / se0 : 0.f;
  float a1 = (end > beg) ? sm1 / se1 : 0.f;
  out[v * H + lane] = a0 + z[v * H + lane];
  out[v * H + lane + 64] = a1 + z[v * H + lane + 64];
}

// ------------- fused MLP: h += (relu(LN(out@w1+b1)))@w2 + b2 -------------
// 256 threads, 32 nodes per block.
__global__ __launch_bounds__(256) void mlp_kernel(
    const float* __restrict__ inbuf, const float* __restrict__ w1,
    const float* __restrict__ b1, const float* __restrict__ mg,
    const float* __restrict__ mb, const float* __restrict__ w2,
    const float* __restrict__ b2, float* __restrict__ h) {
  __shared__ float s_in[32][H];    // 16 KB
  __shared__ float s_mid[32][H2];  // 32 KB
  int tid = threadIdx.x;
  int n0 = blockIdx.x * 32;

  // phase 1: load 32x128 input tile (float4, coalesced)
  for (int i = tid; i < 32 * 32; i += 256) {
    int r = i >> 5, c4 = i & 31;
    int n = n0 + r;
    float4 val = make_float4(0.f, 0.f, 0.f, 0.f);
    if (n < N_NODES) val = ((const float4*)(inbuf + (size_t)n * H))[c4];
    ((float4*)&s_in[r][0])[c4] = val;
  }
  __syncthreads();

  // phase 2: GEMM1 (32x128)@(128x256). thread: 4 cols x 8 nodes.
  int lane = tid & 63;
  int wsub = tid >> 6;  // node sub-block base = wsub*8 (uniform per wave)
  float acc1[4][8];
#pragma unroll
  for (int q = 0; q < 4; q++)
#pragma unroll
    for (int m = 0; m < 8; m++) acc1[q][m] = 0.f;
  for (int k = 0; k < H; k++) {
    float wv0 = w1[k * H2 + lane];
    float wv1 = w1[k * H2 + lane + 64];
    float wv2 = w1[k * H2 + lane + 128];
    float wv3 = w1[k * H2 + lane + 192];
#pragma unroll
    for (int m = 0; m < 8; m++) {
      float a = s_in[wsub * 8 + m][k];  // wave-uniform broadcast
      acc1[0][m] += a * wv0;
      acc1[1][m] += a * wv1;
      acc1[2][m] += a * wv2;
      acc1[3][m] += a * wv3;
    }
  }
#pragma unroll
  for (int q = 0; q < 4; q++)
#pragma unroll
    for (int m = 0; m < 8; m++)
      s_mid[wsub * 8 + m][lane + 64 * q] = acc1[q][m] + b1[lane + 64 * q];
  __syncthreads();

  // phase 3: LayerNorm(256) + relu per node. 8 threads per node.
  {
    int grp = tid >> 3;   // node 0..31
    int sl = tid & 7;
    float vals[32];
    float sum = 0.f;
#pragma unroll
    for (int i = 0; i < 32; i++) {
      float v = s_mid[grp][sl + 8 * i];
      vals[i] = v;
      sum += v;
    }
#pragma unroll
    for (int off = 1; off < 8; off <<= 1) sum += __shfl_xor(sum, off, 64);
    float mu = sum * (1.0f / H2);
    float sq = 0.f;
#pragma unroll
    for (int i = 0; i < 32; i++) {
      float d = vals[i] - mu;
      sq += d * d;
    }
#pragma unroll
    for (int off = 1; off < 8; off <<= 1) sq += __shfl_xor(sq, off, 64);
    float rstd = rsqrtf(sq * (1.0f / H2) + LN_EPS);
#pragma unroll
    for (int i = 0; i < 32; i++) {
      int c = sl + 8 * i;
      float zz = mg[c] * (vals[i] - mu) * rstd + mb[c];
      s_mid[grp][c] = fmaxf(zz, 0.f);
    }
  }
  __syncthreads();

  // phase 4: GEMM2 (32x256)@(256x128). thread: 4 cols x 4 nodes.
  int lane5 = tid & 31;
  int grp8 = tid >> 5;  // node base grp8*4 (2-way broadcast per wave: free)
  float acc2[4][4];
#pragma unroll
  for (int q = 0; q < 4; q++)
#pragma unroll
    for (int m = 0; m < 4; m++) acc2[q][m] = 0.f;
  for (int k = 0; k < H2; k++) {
    float w0 = w2[k * H + lane5];
    float w1v = w2[k * H + lane5 + 32];
    float w2v = w2[k * H + lane5 + 64];
    float w3v = w2[k * H + lane5 + 96];
#pragma unroll
    for (int m = 0; m < 4; m++) {
      float a = s_mid[grp8 * 4 + m][k];
      acc2[0][m] += a * w0;
      acc2[1][m] += a * w1v;
      acc2[2][m] += a * w2v;
      acc2[3][m] += a * w3v;
    }
  }

  // phase 5: h += result + b2
#pragma unroll
  for (int m = 0; m < 4; m++) {
    int n = n0 + grp8 * 4 + m;
    if (n < N_NODES) {
#pragma unroll
      for (int q = 0; q < 4; q++) {
        int c = lane5 + 32 * q;
        h[(size_t)n * H + c] += acc2[q][m] + b2[c];
      }
    }
  }
}

// ---------------- pooling (batch is sorted) ----------------
__global__ __launch_bounds__(128) void pool_kernel(const float* __restrict__ h,
                                                   const int* __restrict__ batch,
                                                   float* __restrict__ pooled) {
  int c = threadIdx.x;  // 0..127
  int n0 = blockIdx.x * 256;
  int nend = n0 + 256;
  if (nend > N_NODES) nend = N_NODES;
  if (n0 >= N_NODES) return;
  float acc = 0.f;
  int cur = batch[n0];
  for (int n = n0; n < nend; n++) {
    int g = batch[n];
    if (g != cur) {
      atomicAdd(&pooled[cur * H + c], acc);
      acc = 0.f;
      cur = g;
    }
    acc += h[(size_t)n * H + c];
  }
  atomicAdd(&pooled[cur * H + c], acc);
}

// ---------------- classifier ----------------
__global__ __launch_bounds__(256) void cls_kernel(const float* __restrict__ pooled,
                                                  const float* __restrict__ cw,
                                                  const float* __restrict__ cb,
                                                  float* __restrict__ out) {
  int tid = threadIdx.x;
  int g = tid >> 2, c = tid & 3;
  float acc = cb[c];
  for (int k = 0; k < H; k++) acc += pooled[g * H + k] * cw[k * NCLS + c];
  out[g * NCLS + c] = acc;
}

extern "C" void kernel_launch(void* const* d_in, const int* in_sizes, int n_in,
                              void* d_out, int out_size, void* d_ws, size_t ws_size,
                              hipStream_t stream) {
  const float* x = (const float*)d_in[0];
  const int* edge_index = (const int*)d_in[1];
  const int* batch = (const int*)d_in[2];
  const float* enc_w = (const float*)d_in[3];
  const float* enc_b = (const float*)d_in[4];
  const float* ln_g = (const float*)d_in[5];
  const float* ln_b = (const float*)d_in[6];
  const float* t = (const float*)d_in[7];
  const float* w1 = (const float*)d_in[8];
  const float* b1 = (const float*)d_in[9];
  const float* mg = (const float*)d_in[10];
  const float* mb = (const float*)d_in[11];
  const float* w2 = (const float*)d_in[12];
  const float* b2 = (const float*)d_in[13];
  const float* cls_w = (const float*)d_in[14];
  const float* cls_b = (const float*)d_in[15];
  float* out = (float*)d_out;

  const int* src = edge_index;            // row 0
  const int* dst = edge_index + N_EDGES;  // row 1

  // workspace layout
  char* ws = (char*)d_ws;
  float* hbuf = (float*)ws;                     // N_NODES*H
  float* zbuf = hbuf + (size_t)N_NODES * H;     // N_NODES*H
  float* obuf = zbuf + (size_t)N_NODES * H;     // N_NODES*H
  float* pooled = obuf + (size_t)N_NODES * H;   // N_GRAPHS*H
  int* rowptr = (int*)(pooled + N_GRAPHS * H);  // N_NODES+1
  int* cnt = rowptr + (N_NODES + 1);            // N_NODES
  int* csr = cnt + N_NODES;                     // N_EDGES

  hipMemsetAsync(cnt, 0, N_NODES * sizeof(int), stream);
  hipMemsetAsync(pooled, 0, N_GRAPHS * H * sizeof(float), stream);

  // encoder
  enc_kernel<<<(N_NODES * H + 255) / 256, 256, 0, stream>>>(x, enc_w, enc_b, hbuf);

  // CSR build (once; reused by all 6 layers)
  hist_kernel<<<(N_EDGES + 255) / 256, 256, 0, stream>>>(dst, cnt);
  scan_kernel<<<1, 1024, 0, stream>>>(cnt, rowptr);
  hipMemsetAsync(cnt, 0, N_NODES * sizeof(int), stream);  // reuse as cursor
  scatter_kernel<<<(N_EDGES + 255) / 256, 256, 0, stream>>>(src, dst, rowptr, cnt, csr);

  const int nodeWaveBlocks = (N_NODES + 3) / 4;  // 4 nodes (waves) per 256-block
  for (int l = 0; l < NL; l++) {
    ln_relu_kernel<<<nodeWaveBlocks, 256, 0, stream>>>(hbuf, ln_g + l * H,
                                                       ln_b + l * H, zbuf);
    agg_kernel<<<nodeWaveBlocks, 256, 0, stream>>>(zbuf, rowptr, csr, t + l, obuf);
    mlp_kernel<<<(N_NODES + 31) / 32, 256, 0, stream>>>(
        obuf, w1 + (size_t)l * H * H2, b1 + (size_t)l * H2, mg + (size_t)l * H2,
        mb + (size_t)l * H2, w2 + (size_t)l * H2 * H, b2 + (size_t)l * H, hbuf);
  }

  pool_kernel<<<(N_NODES + 255) / 256, 128, 0, stream>>>(hbuf, batch, pooled);
  cls_kernel<<<1, 256, 0, stream>>>(pooled, cls_w, cls_b, out);
}

// Round 3
// 1030.048 us; speedup vs baseline: 1.5022x; 1.5022x over previous
//
#include <hip/hip_runtime.h>
#include <hip/hip_bf16.h>

#define N_NODES 50000
#define N_EDGES 640000
#define N_GRAPHS 64
#define IN_FEAT 8
#define H 128
#define H2 256
#define NCLS 4
#define NL 6
#define EPS_MSG 1e-7f
#define LN_EPS 1e-5f

typedef __attribute__((ext_vector_type(4))) float f32x4;
typedef __attribute__((ext_vector_type(8))) short short8;

static __device__ __forceinline__ unsigned short f2bf(float f) {
  union { float f; unsigned int u; } v; v.f = f;
  unsigned int r = v.u + 0x7fffu + ((v.u >> 16) & 1u);
  return (unsigned short)(r >> 16);
}
static __device__ __forceinline__ float bf2f(unsigned int lo16) {
  union { unsigned int u; float f; } v; v.u = lo16 << 16;
  return v.f;
}

// ---------------- encoder: h = x @ enc_w + enc_b (fp32) ----------------
__global__ __launch_bounds__(256) void enc_kernel(
    const float* __restrict__ x, const float* __restrict__ w,
    const float* __restrict__ b, float* __restrict__ h) {
  int idx = blockIdx.x * blockDim.x + threadIdx.x;  // node*H + c
  if (idx >= N_NODES * H) return;
  int n = idx >> 7, c = idx & (H - 1);
  const float* xr = x + n * IN_FEAT;
  float acc = b[c];
#pragma unroll
  for (int k = 0; k < IN_FEAT; k++) acc += xr[k] * w[k * H + c];
  h[idx] = acc;
}

// ---------------- weight convert: fp32 [K][N] -> bf16 [N][K] ----------------
__global__ __launch_bounds__(256) void wconv_kernel(
    const float* __restrict__ w1, const float* __restrict__ w2,
    unsigned short* __restrict__ w1t, unsigned short* __restrict__ w2t) {
  int idx = blockIdx.x * blockDim.x + threadIdx.x;  // over 6*32768
  if (idx >= NL * H * H2) return;
  int l = idx >> 15, r = idx & 32767;
  int n1 = r >> 7, k1 = r & 127;     // w1t [l][n<256][k<128]
  w1t[idx] = f2bf(w1[(l << 15) + k1 * H2 + n1]);
  int n2 = r >> 8, k2 = r & 255;     // w2t [l][n<128][k<256]
  w2t[idx] = f2bf(w2[(l << 15) + k2 * H + n2]);
}

// ---------------- CSR build ----------------
__global__ __launch_bounds__(256) void hist_kernel(const int* __restrict__ dst,
                                                   int* __restrict__ cnt) {
  int e = blockIdx.x * blockDim.x + threadIdx.x;
  if (e < N_EDGES) atomicAdd(&cnt[dst[e]], 1);
}

__global__ __launch_bounds__(1024) void scan_kernel(const int* __restrict__ cnt,
                                                    int* __restrict__ rowptr) {
  __shared__ int wsum[16];
  __shared__ int s_carry;
  int tid = threadIdx.x, lane = tid & 63, w = tid >> 6;
  if (tid == 0) { s_carry = 0; rowptr[0] = 0; }
  __syncthreads();
  for (int base = 0; base < N_NODES; base += 1024) {
    int i = base + tid;
    int v = (i < N_NODES) ? cnt[i] : 0;
    int x = v;
#pragma unroll
    for (int off = 1; off < 64; off <<= 1) {
      int y = __shfl_up(x, off, 64);
      if (lane >= off) x += y;
    }
    if (lane == 63) wsum[w] = x;
    __syncthreads();
    if (w == 0 && lane < 16) {
      int ws = wsum[lane];
#pragma unroll
      for (int off = 1; off < 16; off <<= 1) {
        int y = __shfl_up(ws, off, 64);
        if (lane >= off) ws += y;
      }
      wsum[lane] = ws;
    }
    __syncthreads();
    int waveoff = (w == 0) ? 0 : wsum[w - 1];
    int incl = s_carry + waveoff + x;
    if (i < N_NODES) rowptr[i + 1] = incl;
    __syncthreads();
    if (tid == 1023) s_carry = incl;
    __syncthreads();
  }
}

__global__ __launch_bounds__(256) void scatter_kernel(
    const int* __restrict__ src, const int* __restrict__ dst,
    const int* __restrict__ rowptr, int* __restrict__ cursor,
    int* __restrict__ csr) {
  int e = blockIdx.x * blockDim.x + threadIdx.x;
  if (e < N_EDGES) {
    int d = dst[e];
    int pos = rowptr[d] + atomicAdd(&cursor[d], 1);
    csr[pos] = src[e];
  }
}

// ---------------- per-layer: z = relu(LN(h)) -> bf16 ----------------
__global__ __launch_bounds__(256) void ln_relu_kernel(
    const float* __restrict__ h, const float* __restrict__ g,
    const float* __restrict__ b, unsigned short* __restrict__ z) {
  int node = (blockIdx.x * blockDim.x + threadIdx.x) >> 6;
  int lane = threadIdx.x & 63;
  if (node >= N_NODES) return;
  float2 v = *(const float2*)(h + (size_t)node * H + lane * 2);
  float s = v.x + v.y;
#pragma unroll
  for (int off = 32; off; off >>= 1) s += __shfl_xor(s, off, 64);
  float mu = s * (1.0f / H);
  float d0 = v.x - mu, d1 = v.y - mu;
  float q = d0 * d0 + d1 * d1;
#pragma unroll
  for (int off = 32; off; off >>= 1) q += __shfl_xor(q, off, 64);
  float rstd = rsqrtf(q * (1.0f / H) + LN_EPS);
  float2 gg = *(const float2*)(g + lane * 2);
  float2 bb = *(const float2*)(b + lane * 2);
  float z0 = fmaxf(gg.x * d0 * rstd + bb.x, 0.f);
  float z1 = fmaxf(gg.y * d1 * rstd + bb.y, 0.f);
  unsigned int pack = (unsigned int)f2bf(z0) | ((unsigned int)f2bf(z1) << 16);
  *(unsigned int*)(z + (size_t)node * H + lane * 2) = pack;
}

// ------------- softmax aggregation: out = agg + z (bf16 in/out) -------------
// agg[v] = sum_e(m*e)/sum_e(e), e = exp(m*t), m = z[src]+eps  (z >= 0)
// max-shift dropped: z bounded by sqrt(127) => exp <= ~8e4, safe in fp32.
__global__ __launch_bounds__(256) void agg_kernel(
    const unsigned short* __restrict__ z, const int* __restrict__ rowptr,
    const int* __restrict__ csr, const float* __restrict__ tptr,
    unsigned short* __restrict__ out) {
  int v = (blockIdx.x * blockDim.x + threadIdx.x) >> 6;
  int lane = threadIdx.x & 63;
  if (v >= N_NODES) return;
  float t = *tptr;
  int beg = rowptr[v], end = rowptr[v + 1];
  float se0 = 0.f, sm0 = 0.f, se1 = 0.f, sm1 = 0.f;
  for (int e = beg; e < end; e++) {
    int s = csr[e];
    unsigned int p = *(const unsigned int*)(z + (size_t)s * H + lane * 2);
    float m0 = bf2f(p & 0xffffu) + EPS_MSG;
    float m1 = bf2f(p >> 16) + EPS_MSG;
    float e0 = __expf(m0 * t), e1 = __expf(m1 * t);
    se0 += e0; sm0 += m0 * e0;
    se1 += e1; sm1 += m1 * e1;
  }
  float a0 = (end > beg) ? sm0 / se0 : 0.f;
  float a1 = (end > beg) ? sm1 / se1 : 0.f;
  unsigned int pv = *(const unsigned int*)(z + (size_t)v * H + lane * 2);
  a0 += bf2f(pv & 0xffffu);
  a1 += bf2f(pv >> 16);
  unsigned int pack = (unsigned int)f2bf(a0) | ((unsigned int)f2bf(a1) << 16);
  *(unsigned int*)(out + (size_t)v * H + lane * 2) = pack;
}

// ------------- fused MFMA MLP: h += (relu(LN(in@w1+b1)))@w2 + b2 -------------
// 64 nodes/block, 4 waves. bf16 MFMA 16x16x32, fp32 accum.
// LDS tiles XOR-swizzled: elem ^= (row&7)<<3 (16B granule) on both sides.
__global__ __launch_bounds__(256) void mlp_mfma_kernel(
    const unsigned short* __restrict__ inb,  // [N][128] bf16
    const unsigned short* __restrict__ w1t,  // [256][128] bf16 (B^T)
    const float* __restrict__ b1,
    const float* __restrict__ mg, const float* __restrict__ mb,
    const unsigned short* __restrict__ w2t,  // [128][256] bf16 (B^T)
    const float* __restrict__ b2,
    float* __restrict__ h) {
  __shared__ __align__(16) unsigned short s_in[64 * 128];   // 16KB
  __shared__ __align__(16) unsigned short s_mid[64 * 256];  // 32KB
  __shared__ __align__(16) float s_sumv[64][4];
  __shared__ __align__(16) float s_sqv[64][4];
  int tid = threadIdx.x;
  int w = tid >> 6, l = tid & 63;
  int lr = l & 15, lg = l >> 4;
  int n0 = blockIdx.x * 64;

  // phase 1: stage input tile (16B per thread x 4)
#pragma unroll
  for (int it = 0; it < 4; ++it) {
    int id = it * 256 + tid;       // 0..1023 chunks of 8 bf16
    int row = id >> 4, c8 = (id & 15) * 8;
    int n = n0 + row;
    uint4 val = make_uint4(0, 0, 0, 0);
    if (n < N_NODES) val = *(const uint4*)(inb + (size_t)n * H + c8);
    *(uint4*)(&s_in[row * 128 + (c8 ^ ((row & 7) << 3))]) = val;
  }
  __syncthreads();

  // phase 2: GEMM1 (64x128)@(128x256). wave w -> cols [w*64, w*64+64)
  f32x4 acc1[4][4];
#pragma unroll
  for (int mt = 0; mt < 4; mt++)
#pragma unroll
    for (int nt = 0; nt < 4; nt++) acc1[mt][nt] = (f32x4)(0.f);
#pragma unroll
  for (int ks = 0; ks < 4; ++ks) {
    int k = ks * 32 + lg * 8;
    short8 a[4], bfr[4];
#pragma unroll
    for (int mt = 0; mt < 4; mt++) {
      int row = mt * 16 + lr;
      a[mt] = *(const short8*)(&s_in[row * 128 + (k ^ ((row & 7) << 3))]);
    }
#pragma unroll
    for (int nt = 0; nt < 4; nt++) {
      int col = w * 64 + nt * 16 + lr;
      bfr[nt] = *(const short8*)(w1t + col * 128 + k);
    }
#pragma unroll
    for (int mt = 0; mt < 4; mt++)
#pragma unroll
      for (int nt = 0; nt < 4; nt++)
        acc1[mt][nt] = __builtin_amdgcn_mfma_f32_16x16x32_bf16(
            a[mt], bfr[nt], acc1[mt][nt], 0, 0, 0);
  }

  // bias
  float b1c[4];
#pragma unroll
  for (int nt = 0; nt < 4; nt++) b1c[nt] = b1[w * 64 + nt * 16 + lr];
#pragma unroll
  for (int mt = 0; mt < 4; mt++)
#pragma unroll
    for (int nt = 0; nt < 4; nt++)
#pragma unroll
      for (int j = 0; j < 4; j++) acc1[mt][nt][j] += b1c[nt];

  // in-register LN stats: per-row partial over this wave's 64 cols
#pragma unroll
  for (int mt = 0; mt < 4; mt++)
#pragma unroll
    for (int j = 0; j < 4; j++) {
      float s = 0.f, q = 0.f;
#pragma unroll
      for (int nt = 0; nt < 4; nt++) {
        float vv = acc1[mt][nt][j];
        s += vv; q += vv * vv;
      }
#pragma unroll
      for (int off = 1; off < 16; off <<= 1) {
        s += __shfl_xor(s, off, 64);
        q += __shfl_xor(q, off, 64);
      }
      if (lr == 0) {
        int row = mt * 16 + lg * 4 + j;
        s_sumv[row][w] = s;
        s_sqv[row][w] = q;
      }
    }
  __syncthreads();

  // finalize LN + relu + bf16 -> s_mid (swizzled)
  float mgc[4], mbc[4];
#pragma unroll
  for (int nt = 0; nt < 4; nt++) {
    int col = w * 64 + nt * 16 + lr;
    mgc[nt] = mg[col]; mbc[nt] = mb[col];
  }
#pragma unroll
  for (int mt = 0; mt < 4; mt++)
#pragma unroll
    for (int j = 0; j < 4; j++) {
      int row = mt * 16 + lg * 4 + j;
      float ssum = s_sumv[row][0] + s_sumv[row][1] + s_sumv[row][2] + s_sumv[row][3];
      float qsum = s_sqv[row][0] + s_sqv[row][1] + s_sqv[row][2] + s_sqv[row][3];
      float mu = ssum * (1.0f / H2);
      float var = qsum * (1.0f / H2) - mu * mu;
      float rstd = rsqrtf(var + LN_EPS);
#pragma unroll
      for (int nt = 0; nt < 4; nt++) {
        float vv = (acc1[mt][nt][j] - mu) * rstd * mgc[nt] + mbc[nt];
        vv = fmaxf(vv, 0.f);
        int col = w * 64 + nt * 16 + lr;
        s_mid[row * 256 + (col ^ ((row & 7) << 3))] = f2bf(vv);
      }
    }
  __syncthreads();

  // phase 3: GEMM2 (64x256)@(256x128). wave w -> cols [w*32, w*32+32)
  f32x4 acc2[4][2];
#pragma unroll
  for (int mt = 0; mt < 4; mt++)
#pragma unroll
    for (int nt = 0; nt < 2; nt++) acc2[mt][nt] = (f32x4)(0.f);
#pragma unroll
  for (int ks = 0; ks < 8; ++ks) {
    int k = ks * 32 + lg * 8;
    short8 a[4], bfr[2];
#pragma unroll
    for (int mt = 0; mt < 4; mt++) {
      int row = mt * 16 + lr;
      a[mt] = *(const short8*)(&s_mid[row * 256 + (k ^ ((row & 7) << 3))]);
    }
#pragma unroll
    for (int nt = 0; nt < 2; nt++) {
      int col = w * 32 + nt * 16 + lr;
      bfr[nt] = *(const short8*)(w2t + col * 256 + k);
    }
#pragma unroll
    for (int mt = 0; mt < 4; mt++)
#pragma unroll
      for (int nt = 0; nt < 2; nt++)
        acc2[mt][nt] = __builtin_amdgcn_mfma_f32_16x16x32_bf16(
            a[mt], bfr[nt], acc2[mt][nt], 0, 0, 0);
  }

  // epilogue: h += acc2 + b2
  float b2c[2] = {b2[w * 32 + lr], b2[w * 32 + 16 + lr]};
#pragma unroll
  for (int mt = 0; mt < 4; mt++)
#pragma unroll
    for (int j = 0; j < 4; j++) {
      int n = n0 + mt * 16 + lg * 4 + j;
      if (n < N_NODES) {
#pragma unroll
        for (int nt = 0; nt < 2; nt++) {
          int col = w * 32 + nt * 16 + lr;
          float* hp = h + (size_t)n * H + col;
          *hp += acc2[mt][nt][j] + b2c[nt];
        }
      }
    }
}

// ---------------- pooling (batch is sorted) ----------------
__global__ __launch_bounds__(128) void pool_kernel(const float* __restrict__ h,
                                                   const int* __restrict__ batch,
                                                   float* __restrict__ pooled) {
  int c = threadIdx.x;  // 0..127
  int n0 = blockIdx.x * 256;
  int nend = n0 + 256;
  if (nend > N_NODES) nend = N_NODES;
  if (n0 >= N_NODES) return;
  float acc = 0.f;
  int cur = batch[n0];
  for (int n = n0; n < nend; n++) {
    int g = batch[n];
    if (g != cur) {
      atomicAdd(&pooled[cur * H + c], acc);
      acc = 0.f;
      cur = g;
    }
    acc += h[(size_t)n * H + c];
  }
  atomicAdd(&pooled[cur * H + c], acc);
}

// ---------------- classifier ----------------
__global__ __launch_bounds__(256) void cls_kernel(const float* __restrict__ pooled,
                                                  const float* __restrict__ cw,
                                                  const float* __restrict__ cb,
                                                  float* __restrict__ out) {
  int tid = threadIdx.x;
  int g = tid >> 2, c = tid & 3;
  float acc = cb[c];
  for (int k = 0; k < H; k++) acc += pooled[g * H + k] * cw[k * NCLS + c];
  out[g * NCLS + c] = acc;
}

extern "C" void kernel_launch(void* const* d_in, const int* in_sizes, int n_in,
                              void* d_out, int out_size, void* d_ws, size_t ws_size,
                              hipStream_t stream) {
  const float* x = (const float*)d_in[0];
  const int* edge_index = (const int*)d_in[1];
  const int* batch = (const int*)d_in[2];
  const float* enc_w = (const float*)d_in[3];
  const float* enc_b = (const float*)d_in[4];
  const float* ln_g = (const float*)d_in[5];
  const float* ln_b = (const float*)d_in[6];
  const float* t = (const float*)d_in[7];
  const float* w1 = (const float*)d_in[8];
  const float* b1 = (const float*)d_in[9];
  const float* mg = (const float*)d_in[10];
  const float* mb = (const float*)d_in[11];
  const float* w2 = (const float*)d_in[12];
  const float* b2 = (const float*)d_in[13];
  const float* cls_w = (const float*)d_in[14];
  const float* cls_b = (const float*)d_in[15];
  float* out = (float*)d_out;

  const int* src = edge_index;            // row 0
  const int* dst = edge_index + N_EDGES;  // row 1

  // workspace layout (all offsets 16B-aligned)
  char* ws = (char*)d_ws;
  float* hbuf = (float*)ws;                                  // N*H fp32
  unsigned short* zbuf = (unsigned short*)(hbuf + (size_t)N_NODES * H);
  unsigned short* obuf = zbuf + (size_t)N_NODES * H;
  unsigned short* w1t = obuf + (size_t)N_NODES * H;          // NL*H2*H bf16
  unsigned short* w2t = w1t + (size_t)NL * H * H2;           // NL*H*H2 bf16
  float* pooled = (float*)(w2t + (size_t)NL * H * H2);
  int* rowptr = (int*)(pooled + N_GRAPHS * H);
  int* cnt = rowptr + (N_NODES + 1);
  int* csr = cnt + N_NODES;

  hipMemsetAsync(cnt, 0, N_NODES * sizeof(int), stream);
  hipMemsetAsync(pooled, 0, N_GRAPHS * H * sizeof(float), stream);

  enc_kernel<<<(N_NODES * H + 255) / 256, 256, 0, stream>>>(x, enc_w, enc_b, hbuf);
  wconv_kernel<<<(NL * H * H2 + 255) / 256, 256, 0, stream>>>(w1, w2, w1t, w2t);

  hist_kernel<<<(N_EDGES + 255) / 256, 256, 0, stream>>>(dst, cnt);
  scan_kernel<<<1, 1024, 0, stream>>>(cnt, rowptr);
  hipMemsetAsync(cnt, 0, N_NODES * sizeof(int), stream);  // reuse as cursor
  scatter_kernel<<<(N_EDGES + 255) / 256, 256, 0, stream>>>(src, dst, rowptr, cnt, csr);

  const int nodeWaveBlocks = (N_NODES + 3) / 4;  // 4 nodes per 256-block
  for (int l = 0; l < NL; l++) {
    ln_relu_kernel<<<nodeWaveBlocks, 256, 0, stream>>>(hbuf, ln_g + l * H,
                                                       ln_b + l * H, zbuf);
    agg_kernel<<<nodeWaveBlocks, 256, 0, stream>>>(zbuf, rowptr, csr, t + l, obuf);
    mlp_mfma_kernel<<<(N_NODES + 63) / 64, 256, 0, stream>>>(
        obuf, w1t + (size_t)l * H * H2, b1 + (size_t)l * H2, mg + (size_t)l * H2,
        mb + (size_t)l * H2, w2t + (size_t)l * H2 * H, b2 + (size_t)l * H, hbuf);
  }

  pool_kernel<<<(N_NODES + 255) / 256, 128, 0, stream>>>(hbuf, batch, pooled);
  cls_kernel<<<1, 256, 0, stream>>>(pooled, cls_w, cls_b, out);
}

// Round 9
// 813.673 us; speedup vs baseline: 1.9016x; 1.2659x over previous
//
#include <hip/hip_runtime.h>
#include <hip/hip_bf16.h>

#define N_NODES 50000
#define N_PAD 50048  // multiple of 64 for full MLP tiles
#define N_EDGES 640000
#define N_GRAPHS 64
#define IN_FEAT 8
#define H 128
#define H2 256
#define NCLS 4
#define NL 6
#define EPS_MSG 1e-7f
#define LN_EPS 1e-5f

typedef __attribute__((ext_vector_type(4))) float f32x4;
typedef __attribute__((ext_vector_type(8))) short short8;

static __device__ __forceinline__ unsigned short f2bf(float f) {
  union { float f; unsigned int u; } v; v.f = f;
  unsigned int r = v.u + 0x7fffu + ((v.u >> 16) & 1u);
  return (unsigned short)(r >> 16);
}
static __device__ __forceinline__ float bf2f(unsigned int lo16) {
  union { unsigned int u; float f; } v; v.u = lo16 << 16;
  return v.f;
}

// ------------- encoder fused with layer-0 LN: h = x@W+b; z0 = relu(LN(h)) -------------
__global__ __launch_bounds__(256) void enc_ln_kernel(
    const float* __restrict__ x, const float* __restrict__ w,
    const float* __restrict__ b, const float* __restrict__ g,
    const float* __restrict__ lb, float* __restrict__ h,
    unsigned short* __restrict__ z) {
  int node = (blockIdx.x * blockDim.x + threadIdx.x) >> 6;
  int lane = threadIdx.x & 63;
  if (node >= N_NODES) return;
  const float* xr = x + (size_t)node * IN_FEAT;
  float xv[IN_FEAT];
#pragma unroll
  for (int k = 0; k < IN_FEAT; k++) xv[k] = xr[k];  // wave-uniform
  int c0 = lane * 2;
  float2 acc = *(const float2*)(b + c0);
#pragma unroll
  for (int k = 0; k < IN_FEAT; k++) {
    float2 wv = *(const float2*)(w + k * H + c0);
    acc.x += xv[k] * wv.x;
    acc.y += xv[k] * wv.y;
  }
  *(float2*)(h + (size_t)node * H + c0) = acc;
  float s = acc.x + acc.y;
#pragma unroll
  for (int off = 32; off; off >>= 1) s += __shfl_xor(s, off, 64);
  float mu = s * (1.0f / H);
  float d0 = acc.x - mu, d1 = acc.y - mu;
  float q = d0 * d0 + d1 * d1;
#pragma unroll
  for (int off = 32; off; off >>= 1) q += __shfl_xor(q, off, 64);
  float rstd = rsqrtf(q * (1.0f / H) + LN_EPS);
  float2 gg = *(const float2*)(g + c0);
  float2 bb = *(const float2*)(lb + c0);
  float z0 = fmaxf(gg.x * d0 * rstd + bb.x, 0.f);
  float z1 = fmaxf(gg.y * d1 * rstd + bb.y, 0.f);
  unsigned int pack = (unsigned int)f2bf(z0) | ((unsigned int)f2bf(z1) << 16);
  *(unsigned int*)(z + (size_t)node * H + c0) = pack;
}

// ---------------- weight convert: fp32 [K][N] -> bf16 [N][K] ----------------
__global__ __launch_bounds__(256) void wconv_kernel(
    const float* __restrict__ w1, const float* __restrict__ w2,
    unsigned short* __restrict__ w1t, unsigned short* __restrict__ w2t) {
  int idx = blockIdx.x * blockDim.x + threadIdx.x;  // over 6*32768
  if (idx >= NL * H * H2) return;
  int l = idx >> 15, r = idx & 32767;
  int n1 = r >> 7, k1 = r & 127;     // w1t [l][n<256][k<128]
  w1t[idx] = f2bf(w1[(l << 15) + k1 * H2 + n1]);
  int n2 = r >> 8, k2 = r & 255;     // w2t [l][n<128][k<256]
  w2t[idx] = f2bf(w2[(l << 15) + k2 * H + n2]);
}

// ---------------- CSR build ----------------
__global__ __launch_bounds__(256) void hist_kernel(const int* __restrict__ dst,
                                                   int* __restrict__ cnt) {
  int e = blockIdx.x * blockDim.x + threadIdx.x;
  if (e < N_EDGES) atomicAdd(&cnt[dst[e]], 1);
}

__global__ __launch_bounds__(1024) void scan_kernel(const int* __restrict__ cnt,
                                                    int* __restrict__ rowptr) {
  __shared__ int wsum[16];
  __shared__ int s_carry;
  int tid = threadIdx.x, lane = tid & 63, w = tid >> 6;
  if (tid == 0) { s_carry = 0; rowptr[0] = 0; }
  __syncthreads();
  for (int base = 0; base < N_NODES; base += 1024) {
    int i = base + tid;
    int v = (i < N_NODES) ? cnt[i] : 0;
    int x = v;
#pragma unroll
    for (int off = 1; off < 64; off <<= 1) {
      int y = __shfl_up(x, off, 64);
      if (lane >= off) x += y;
    }
    if (lane == 63) wsum[w] = x;
    __syncthreads();
    if (w == 0 && lane < 16) {
      int ws = wsum[lane];
#pragma unroll
      for (int off = 1; off < 16; off <<= 1) {
        int y = __shfl_up(ws, off, 64);
        if (lane >= off) ws += y;
      }
      wsum[lane] = ws;
    }
    __syncthreads();
    int waveoff = (w == 0) ? 0 : wsum[w - 1];
    int incl = s_carry + waveoff + x;
    if (i < N_NODES) rowptr[i + 1] = incl;
    __syncthreads();
    if (tid == 1023) s_carry = incl;
    __syncthreads();
  }
}

__global__ __launch_bounds__(256) void scatter_kernel(
    const int* __restrict__ src, const int* __restrict__ dst,
    const int* __restrict__ rowptr, int* __restrict__ cursor,
    int* __restrict__ csr) {
  int e = blockIdx.x * blockDim.x + threadIdx.x;
  if (e < N_EDGES) {
    int d = dst[e];
    int pos = rowptr[d] + atomicAdd(&cursor[d], 1);
    csr[pos] = src[e];
  }
}

// ------------- softmax aggregation: out = agg + z (bf16 in/out) -------------
// 4-deep unrolled edge loop: independent gathers in flight to hide latency.
#define AGG_EDGE(p)                              \
  {                                              \
    float m0 = bf2f((p) & 0xffffu) + EPS_MSG;    \
    float m1 = bf2f((p) >> 16) + EPS_MSG;        \
    float e0 = __expf(m0 * t), e1 = __expf(m1 * t); \
    se0 += e0; sm0 += m0 * e0;                   \
    se1 += e1; sm1 += m1 * e1;                   \
  }

__global__ __launch_bounds__(256) void agg_kernel(
    const unsigned short* __restrict__ z, const int* __restrict__ rowptr,
    const int* __restrict__ csr, const float* __restrict__ tptr,
    unsigned short* __restrict__ out) {
  int v = (blockIdx.x * blockDim.x + threadIdx.x) >> 6;
  int lane = threadIdx.x & 63;
  if (v >= N_PAD) return;
  if (v >= N_NODES) {  // zero pad rows so MLP tiles are fully valid
    *(unsigned int*)(out + (size_t)v * H + lane * 2) = 0;
    return;
  }
  float t = *tptr;
  int beg = rowptr[v], end = rowptr[v + 1];
  float se0 = 0.f, sm0 = 0.f, se1 = 0.f, sm1 = 0.f;
  int e = beg;
  for (; e + 4 <= end; e += 4) {
    int s0 = csr[e], s1 = csr[e + 1], s2 = csr[e + 2], s3 = csr[e + 3];
    unsigned int p0 = *(const unsigned int*)(z + (size_t)s0 * H + lane * 2);
    unsigned int p1 = *(const unsigned int*)(z + (size_t)s1 * H + lane * 2);
    unsigned int p2 = *(const unsigned int*)(z + (size_t)s2 * H + lane * 2);
    unsigned int p3 = *(const unsigned int*)(z + (size_t)s3 * H + lane * 2);
    AGG_EDGE(p0) AGG_EDGE(p1) AGG_EDGE(p2) AGG_EDGE(p3)
  }
  for (; e < end; e++) {
    int s = csr[e];
    unsigned int p = *(const unsigned int*)(z + (size_t)s * H + lane * 2);
    AGG_EDGE(p)
  }
  float a0 = (end > beg) ? sm0 / se0 : 0.f;
  float a1 = (end > beg) ? sm1 / se1 : 0.f;
  unsigned int pv = *(const unsigned int*)(z + (size_t)v * H + lane * 2);
  a0 += bf2f(pv & 0xffffu);
  a1 += bf2f(pv >> 16);
  unsigned int pack = (unsigned int)f2bf(a0) | ((unsigned int)f2bf(a1) << 16);
  *(unsigned int*)(out + (size_t)v * H + lane * 2) = pack;
}

// ------ fused MFMA MLP: h += (relu(LN(in@w1+b1)))@w2 + b2; z_next = relu(LN(h)) ------
// 64 nodes/block, 4 waves. bf16 MFMA 16x16x32, fp32 accum.
// LDS tiles XOR-swizzled: elem ^= (row&7)<<3 (16B granule) on both sides.
__global__ __launch_bounds__(256) void mlp_mfma_kernel(
    const unsigned short* __restrict__ inb,  // [N_PAD][128] bf16
    const unsigned short* __restrict__ w1t,  // [256][128] bf16 (B^T)
    const float* __restrict__ b1,
    const float* __restrict__ mg, const float* __restrict__ mb,
    const unsigned short* __restrict__ w2t,  // [128][256] bf16 (B^T)
    const float* __restrict__ b2,
    float* __restrict__ h,
    const float* __restrict__ g_next, const float* __restrict__ b_next,
    unsigned short* __restrict__ zout) {  // nullptr on last layer
  __shared__ __align__(16) unsigned short s_in[64 * 128];   // 16KB
  __shared__ __align__(16) unsigned short s_mid[64 * 256];  // 32KB
  __shared__ __align__(16) float s_sumv[64][4];
  __shared__ __align__(16) float s_sqv[64][4];
  int tid = threadIdx.x;
  int w = tid >> 6, l = tid & 63;
  int lr = l & 15, lg = l >> 4;
  int n0 = blockIdx.x * 64;

  // phase 1: stage input tile (16B per thread x 4); rows always valid (padded)
#pragma unroll
  for (int it = 0; it < 4; ++it) {
    int id = it * 256 + tid;       // 0..1023 chunks of 8 bf16
    int row = id >> 4, c8 = (id & 15) * 8;
    uint4 val = *(const uint4*)(inb + (size_t)(n0 + row) * H + c8);
    *(uint4*)(&s_in[row * 128 + (c8 ^ ((row & 7) << 3))]) = val;
  }
  __syncthreads();

  // phase 2: GEMM1 (64x128)@(128x256). wave w -> cols [w*64, w*64+64)
  f32x4 acc1[4][4];
#pragma unroll
  for (int mt = 0; mt < 4; mt++)
#pragma unroll
    for (int nt = 0; nt < 4; nt++) acc1[mt][nt] = (f32x4)(0.f);
#pragma unroll
  for (int ks = 0; ks < 4; ++ks) {
    int k = ks * 32 + lg * 8;
    short8 a[4], bfr[4];
#pragma unroll
    for (int mt = 0; mt < 4; mt++) {
      int row = mt * 16 + lr;
      a[mt] = *(const short8*)(&s_in[row * 128 + (k ^ ((row & 7) << 3))]);
    }
#pragma unroll
    for (int nt = 0; nt < 4; nt++) {
      int col = w * 64 + nt * 16 + lr;
      bfr[nt] = *(const short8*)(w1t + col * 128 + k);
    }
#pragma unroll
    for (int mt = 0; mt < 4; mt++)
#pragma unroll
      for (int nt = 0; nt < 4; nt++)
        acc1[mt][nt] = __builtin_amdgcn_mfma_f32_16x16x32_bf16(
            a[mt], bfr[nt], acc1[mt][nt], 0, 0, 0);
  }

  // bias
  float b1c[4];
#pragma unroll
  for (int nt = 0; nt < 4; nt++) b1c[nt] = b1[w * 64 + nt * 16 + lr];
#pragma unroll
  for (int mt = 0; mt < 4; mt++)
#pragma unroll
    for (int nt = 0; nt < 4; nt++)
#pragma unroll
      for (int j = 0; j < 4; j++) acc1[mt][nt][j] += b1c[nt];

  // in-register LN stats: per-row partial over this wave's 64 cols
#pragma unroll
  for (int mt = 0; mt < 4; mt++)
#pragma unroll
    for (int j = 0; j < 4; j++) {
      float s = 0.f, q = 0.f;
#pragma unroll
      for (int nt = 0; nt < 4; nt++) {
        float vv = acc1[mt][nt][j];
        s += vv; q += vv * vv;
      }
#pragma unroll
      for (int off = 1; off < 16; off <<= 1) {
        s += __shfl_xor(s, off, 64);
        q += __shfl_xor(q, off, 64);
      }
      if (lr == 0) {
        int row = mt * 16 + lg * 4 + j;
        s_sumv[row][w] = s;
        s_sqv[row][w] = q;
      }
    }
  __syncthreads();

  // finalize mid-LN + relu + bf16 -> s_mid (swizzled)
  float mgc[4], mbc[4];
#pragma unroll
  for (int nt = 0; nt < 4; nt++) {
    int col = w * 64 + nt * 16 + lr;
    mgc[nt] = mg[col]; mbc[nt] = mb[col];
  }
#pragma unroll
  for (int mt = 0; mt < 4; mt++)
#pragma unroll
    for (int j = 0; j < 4; j++) {
      int row = mt * 16 + lg * 4 + j;
      float ssum = s_sumv[row][0] + s_sumv[row][1] + s_sumv[row][2] + s_sumv[row][3];
      float qsum = s_sqv[row][0] + s_sqv[row][1] + s_sqv[row][2] + s_sqv[row][3];
      float mu = ssum * (1.0f / H2);
      float var = qsum * (1.0f / H2) - mu * mu;
      float rstd = rsqrtf(fmaxf(var, 0.f) + LN_EPS);
#pragma unroll
      for (int nt = 0; nt < 4; nt++) {
        float vv = (acc1[mt][nt][j] - mu) * rstd * mgc[nt] + mbc[nt];
        vv = fmaxf(vv, 0.f);
        int col = w * 64 + nt * 16 + lr;
        s_mid[row * 256 + (col ^ ((row & 7) << 3))] = f2bf(vv);
      }
    }
  __syncthreads();

  // phase 3: GEMM2 (64x256)@(256x128). wave w -> cols [w*32, w*32+32)
  f32x4 acc2[4][2];
#pragma unroll
  for (int mt = 0; mt < 4; mt++)
#pragma unroll
    for (int nt = 0; nt < 2; nt++) acc2[mt][nt] = (f32x4)(0.f);
#pragma unroll
  for (int ks = 0; ks < 8; ++ks) {
    int k = ks * 32 + lg * 8;
    short8 a[4], bfr[2];
#pragma unroll
    for (int mt = 0; mt < 4; mt++) {
      int row = mt * 16 + lr;
      a[mt] = *(const short8*)(&s_mid[row * 256 + (k ^ ((row & 7) << 3))]);
    }
#pragma unroll
    for (int nt = 0; nt < 2; nt++) {
      int col = w * 32 + nt * 16 + lr;
      bfr[nt] = *(const short8*)(w2t + col * 256 + k);
    }
#pragma unroll
    for (int mt = 0; mt < 4; mt++)
#pragma unroll
      for (int nt = 0; nt < 2; nt++)
        acc2[mt][nt] = __builtin_amdgcn_mfma_f32_16x16x32_bf16(
            a[mt], bfr[nt], acc2[mt][nt], 0, 0, 0);
  }

  // epilogue: hv = h_old + acc2 + b2 -> store h; then next-layer LN -> zout
  float b2c[2] = {b2[w * 32 + lr], b2[w * 32 + 16 + lr]};
#pragma unroll
  for (int mt = 0; mt < 4; mt++)
#pragma unroll
    for (int j = 0; j < 4; j++) {
      int n = n0 + mt * 16 + lg * 4 + j;
      bool valid = (n < N_NODES);
#pragma unroll
      for (int nt = 0; nt < 2; nt++) {
        int col = w * 32 + nt * 16 + lr;
        float hold = valid ? h[(size_t)n * H + col] : 0.f;
        float hv = hold + acc2[mt][nt][j] + b2c[nt];
        acc2[mt][nt][j] = hv;
        if (valid) h[(size_t)n * H + col] = hv;
      }
    }

  if (zout) {
    // per-row stats over 128 cols (this wave owns 32)
#pragma unroll
    for (int mt = 0; mt < 4; mt++)
#pragma unroll
      for (int j = 0; j < 4; j++) {
        float s = acc2[mt][0][j] + acc2[mt][1][j];
        float q = acc2[mt][0][j] * acc2[mt][0][j] + acc2[mt][1][j] * acc2[mt][1][j];
#pragma unroll
        for (int off = 1; off < 16; off <<= 1) {
          s += __shfl_xor(s, off, 64);
          q += __shfl_xor(q, off, 64);
        }
        if (lr == 0) {
          int row = mt * 16 + lg * 4 + j;
          s_sumv[row][w] = s;
          s_sqv[row][w] = q;
        }
      }
    __syncthreads();
    float gc[2] = {g_next[w * 32 + lr], g_next[w * 32 + 16 + lr]};
    float bc[2] = {b_next[w * 32 + lr], b_next[w * 32 + 16 + lr]};
#pragma unroll
    for (int mt = 0; mt < 4; mt++)
#pragma unroll
      for (int j = 0; j < 4; j++) {
        int row = mt * 16 + lg * 4 + j;
        float ssum = s_sumv[row][0] + s_sumv[row][1] + s_sumv[row][2] + s_sumv[row][3];
        float qsum = s_sqv[row][0] + s_sqv[row][1] + s_sqv[row][2] + s_sqv[row][3];
        float mu = ssum * (1.0f / H);
        float var = qsum * (1.0f / H) - mu * mu;
        float rstd = rsqrtf(fmaxf(var, 0.f) + LN_EPS);
#pragma unroll
        for (int nt = 0; nt < 2; nt++) {
          int col = w * 32 + nt * 16 + lr;
          float zz = fmaxf(gc[nt] * (acc2[mt][nt][j] - mu) * rstd + bc[nt], 0.f);
          s_in[row * 128 + (col ^ ((row & 7) << 3))] = f2bf(zz);
        }
      }
    __syncthreads();
    // coalesced 16B z store
#pragma unroll
    for (int it = 0; it < 4; ++it) {
      int id = it * 256 + tid;
      int row = id >> 4, c8 = (id & 15) * 8;
      int n = n0 + row;
      if (n < N_NODES) {
        uint4 val = *(const uint4*)(&s_in[row * 128 + (c8 ^ ((row & 7) << 3))]);
        *(uint4*)(zout + (size_t)n * H + c8) = val;
      }
    }
  }
}

// ---------------- pooling (batch is sorted): 64-node chunks ----------------
__global__ __launch_bounds__(128) void pool_kernel(const float* __restrict__ h,
                                                   const int* __restrict__ batch,
                                                   float* __restrict__ pooled) {
  int c = threadIdx.x;  // 0..127
  int n0 = blockIdx.x * 64;
  int nend = n0 + 64;
  if (nend > N_NODES) nend = N_NODES;
  if (n0 >= N_NODES) return;
  float acc = 0.f;
  int cur = batch[n0];
  for (int n = n0; n < nend; n++) {
    int g = batch[n];
    if (g != cur) {
      atomicAdd(&pooled[cur * H + c], acc);
      acc = 0.f;
      cur = g;
    }
    acc += h[(size_t)n * H + c];
  }
  atomicAdd(&pooled[cur * H + c], acc);
}

// ---------------- classifier ----------------
__global__ __launch_bounds__(256) void cls_kernel(const float* __restrict__ pooled,
                                                  const float* __restrict__ cw,
                                                  const float* __restrict__ cb,
                                                  float* __restrict__ out) {
  int tid = threadIdx.x;
  int g = tid >> 2, c = tid & 3;
  float acc = cb[c];
  for (int k = 0; k < H; k++) acc += pooled[g * H + k] * cw[k * NCLS + c];
  out[g * NCLS + c] = acc;
}

extern "C" void kernel_launch(void* const* d_in, const int* in_sizes, int n_in,
                              void* d_out, int out_size, void* d_ws, size_t ws_size,
                              hipStream_t stream) {
  const float* x = (const float*)d_in[0];
  const int* edge_index = (const int*)d_in[1];
  const int* batch = (const int*)d_in[2];
  const float* enc_w = (const float*)d_in[3];
  const float* enc_b = (const float*)d_in[4];
  const float* ln_g = (const float*)d_in[5];
  const float* ln_b = (const float*)d_in[6];
  const float* t = (const float*)d_in[7];
  const float* w1 = (const float*)d_in[8];
  const float* b1 = (const float*)d_in[9];
  const float* mg = (const float*)d_in[10];
  const float* mb = (const float*)d_in[11];
  const float* w2 = (const float*)d_in[12];
  const float* b2 = (const float*)d_in[13];
  const float* cls_w = (const float*)d_in[14];
  const float* cls_b = (const float*)d_in[15];
  float* out = (float*)d_out;

  const int* src = edge_index;            // row 0
  const int* dst = edge_index + N_EDGES;  // row 1

  // workspace layout (all offsets 16B-aligned)
  char* ws = (char*)d_ws;
  float* hbuf = (float*)ws;                                  // N*H fp32
  unsigned short* zbuf = (unsigned short*)(hbuf + (size_t)N_NODES * H);
  unsigned short* obuf = zbuf + (size_t)N_NODES * H;         // N_PAD*H bf16
  unsigned short* w1t = obuf + (size_t)N_PAD * H;            // NL*H2*H bf16
  unsigned short* w2t = w1t + (size_t)NL * H * H2;           // NL*H*H2 bf16
  float* pooled = (float*)(w2t + (size_t)NL * H * H2);
  int* rowptr = (int*)(pooled + N_GRAPHS * H);
  int* cnt = rowptr + (N_NODES + 1);
  int* csr = cnt + N_NODES;

  hipMemsetAsync(cnt, 0, N_NODES * sizeof(int), stream);
  hipMemsetAsync(pooled, 0, N_GRAPHS * H * sizeof(float), stream);

  enc_ln_kernel<<<(N_NODES + 3) / 4, 256, 0, stream>>>(x, enc_w, enc_b, ln_g, ln_b,
                                                       hbuf, zbuf);
  wconv_kernel<<<(NL * H * H2 + 255) / 256, 256, 0, stream>>>(w1, w2, w1t, w2t);

  hist_kernel<<<(N_EDGES + 255) / 256, 256, 0, stream>>>(dst, cnt);
  scan_kernel<<<1, 1024, 0, stream>>>(cnt, rowptr);
  hipMemsetAsync(cnt, 0, N_NODES * sizeof(int), stream);  // reuse as cursor
  scatter_kernel<<<(N_EDGES + 255) / 256, 256, 0, stream>>>(src, dst, rowptr, cnt, csr);

  for (int l = 0; l < NL; l++) {
    agg_kernel<<<N_PAD / 4, 256, 0, stream>>>(zbuf, rowptr, csr, t + l, obuf);
    const float* gn = (l + 1 < NL) ? ln_g + (l + 1) * H : nullptr;
    const float* bn = (l + 1 < NL) ? ln_b + (l + 1) * H : nullptr;
    unsigned short* zo = (l + 1 < NL) ? zbuf : nullptr;
    mlp_mfma_kernel<<<N_PAD / 64, 256, 0, stream>>>(
        obuf, w1t + (size_t)l * H * H2, b1 + (size_t)l * H2, mg + (size_t)l * H2,
        mb + (size_t)l * H2, w2t + (size_t)l * H2 * H, b2 + (size_t)l * H, hbuf,
        gn, bn, zo);
  }

  pool_kernel<<<(N_NODES + 63) / 64, 128, 0, stream>>>(hbuf, batch, pooled);
  cls_kernel<<<1, 256, 0, stream>>>(pooled, cls_w, cls_b, out);
}

// Round 14
// 810.859 us; speedup vs baseline: 1.9082x; 1.0035x over previous
//
#include <hip/hip_runtime.h>
#include <hip/hip_bf16.h>

#define N_NODES 50000
#define N_PAD 50048  // multiple of 64 for full MLP tiles
#define N_EDGES 640000
#define N_GRAPHS 64
#define IN_FEAT 8
#define H 128
#define H2 256
#define NCLS 4
#define NL 6
#define EPS_MSG 1e-7f
#define LN_EPS 1e-5f

typedef __attribute__((ext_vector_type(4))) float f32x4;
typedef __attribute__((ext_vector_type(8))) short short8;

static __device__ __forceinline__ unsigned short f2bf(float f) {
  union { float f; unsigned int u; } v; v.f = f;
  unsigned int r = v.u + 0x7fffu + ((v.u >> 16) & 1u);
  return (unsigned short)(r >> 16);
}
static __device__ __forceinline__ float bf2f(unsigned int lo16) {
  union { unsigned int u; float f; } v; v.u = lo16 << 16;
  return v.f;
}

// ------------- encoder fused with layer-0 LN: h = x@W+b; z0 = relu(LN(h)) -------------
__global__ __launch_bounds__(256) void enc_ln_kernel(
    const float* __restrict__ x, const float* __restrict__ w,
    const float* __restrict__ b, const float* __restrict__ g,
    const float* __restrict__ lb, float* __restrict__ h,
    unsigned short* __restrict__ z) {
  int node = (blockIdx.x * blockDim.x + threadIdx.x) >> 6;
  int lane = threadIdx.x & 63;
  if (node >= N_NODES) return;
  const float* xr = x + (size_t)node * IN_FEAT;
  float xv[IN_FEAT];
#pragma unroll
  for (int k = 0; k < IN_FEAT; k++) xv[k] = xr[k];  // wave-uniform
  int c0 = lane * 2;
  float2 acc = *(const float2*)(b + c0);
#pragma unroll
  for (int k = 0; k < IN_FEAT; k++) {
    float2 wv = *(const float2*)(w + k * H + c0);
    acc.x += xv[k] * wv.x;
    acc.y += xv[k] * wv.y;
  }
  *(float2*)(h + (size_t)node * H + c0) = acc;
  float s = acc.x + acc.y;
#pragma unroll
  for (int off = 32; off; off >>= 1) s += __shfl_xor(s, off, 64);
  float mu = s * (1.0f / H);
  float d0 = acc.x - mu, d1 = acc.y - mu;
  float q = d0 * d0 + d1 * d1;
#pragma unroll
  for (int off = 32; off; off >>= 1) q += __shfl_xor(q, off, 64);
  float rstd = rsqrtf(q * (1.0f / H) + LN_EPS);
  float2 gg = *(const float2*)(g + c0);
  float2 bb = *(const float2*)(lb + c0);
  float z0 = fmaxf(gg.x * d0 * rstd + bb.x, 0.f);
  float z1 = fmaxf(gg.y * d1 * rstd + bb.y, 0.f);
  unsigned int pack = (unsigned int)f2bf(z0) | ((unsigned int)f2bf(z1) << 16);
  *(unsigned int*)(z + (size_t)node * H + c0) = pack;
}

// ---------------- weight convert: fp32 [K][N] -> bf16 [N][K] ----------------
__global__ __launch_bounds__(256) void wconv_kernel(
    const float* __restrict__ w1, const float* __restrict__ w2,
    unsigned short* __restrict__ w1t, unsigned short* __restrict__ w2t) {
  int idx = blockIdx.x * blockDim.x + threadIdx.x;  // over 6*32768
  if (idx >= NL * H * H2) return;
  int l = idx >> 15, r = idx & 32767;
  int n1 = r >> 7, k1 = r & 127;     // w1t [l][n<256][k<128]
  w1t[idx] = f2bf(w1[(l << 15) + k1 * H2 + n1]);
  int n2 = r >> 8, k2 = r & 255;     // w2t [l][n<128][k<256]
  w2t[idx] = f2bf(w2[(l << 15) + k2 * H + n2]);
}

// ---------------- CSR build ----------------
__global__ __launch_bounds__(256) void hist_kernel(const int* __restrict__ dst,
                                                   int* __restrict__ cnt) {
  int e = blockIdx.x * blockDim.x + threadIdx.x;
  if (e < N_EDGES) atomicAdd(&cnt[dst[e]], 1);
}

__global__ __launch_bounds__(1024) void scan_kernel(const int* __restrict__ cnt,
                                                    int* __restrict__ rowptr) {
  __shared__ int wsum[16];
  __shared__ int s_carry;
  int tid = threadIdx.x, lane = tid & 63, w = tid >> 6;
  if (tid == 0) { s_carry = 0; rowptr[0] = 0; }
  __syncthreads();
  for (int base = 0; base < N_NODES; base += 1024) {
    int i = base + tid;
    int v = (i < N_NODES) ? cnt[i] : 0;
    int x = v;
#pragma unroll
    for (int off = 1; off < 64; off <<= 1) {
      int y = __shfl_up(x, off, 64);
      if (lane >= off) x += y;
    }
    if (lane == 63) wsum[w] = x;
    __syncthreads();
    if (w == 0 && lane < 16) {
      int ws = wsum[lane];
#pragma unroll
      for (int off = 1; off < 16; off <<= 1) {
        int y = __shfl_up(ws, off, 64);
        if (lane >= off) ws += y;
      }
      wsum[lane] = ws;
    }
    __syncthreads();
    int waveoff = (w == 0) ? 0 : wsum[w - 1];
    int incl = s_carry + waveoff + x;
    if (i < N_NODES) rowptr[i + 1] = incl;
    __syncthreads();
    if (tid == 1023) s_carry = incl;
    __syncthreads();
  }
}

__global__ __launch_bounds__(256) void scatter_kernel(
    const int* __restrict__ src, const int* __restrict__ dst,
    const int* __restrict__ rowptr, int* __restrict__ cursor,
    int* __restrict__ csr) {
  int e = blockIdx.x * blockDim.x + threadIdx.x;
  if (e < N_EDGES) {
    int d = dst[e];
    int pos = rowptr[d] + atomicAdd(&cursor[d], 1);
    csr[pos] = src[e];
  }
}

// ------------- softmax aggregation: out = agg + z (bf16 in/out) -------------
// 8-deep unrolled edge loop: independent gathers in flight to hide latency.
#define AGG_EDGE(p)                              \
  {                                              \
    float m0 = bf2f((p) & 0xffffu) + EPS_MSG;    \
    float m1 = bf2f((p) >> 16) + EPS_MSG;        \
    float e0 = __expf(m0 * t), e1 = __expf(m1 * t); \
    se0 += e0; sm0 += m0 * e0;                   \
    se1 += e1; sm1 += m1 * e1;                   \
  }

__global__ __launch_bounds__(256) void agg_kernel(
    const unsigned short* __restrict__ z, const int* __restrict__ rowptr,
    const int* __restrict__ csr, const float* __restrict__ tptr,
    unsigned short* __restrict__ out) {
  int v = (blockIdx.x * blockDim.x + threadIdx.x) >> 6;
  int lane = threadIdx.x & 63;
  if (v >= N_PAD) return;
  if (v >= N_NODES) {  // zero pad rows so MLP tiles are fully valid
    *(unsigned int*)(out + (size_t)v * H + lane * 2) = 0;
    return;
  }
  float t = *tptr;
  int beg = rowptr[v], end = rowptr[v + 1];
  float se0 = 0.f, sm0 = 0.f, se1 = 0.f, sm1 = 0.f;
  int e = beg;
  for (; e + 8 <= end; e += 8) {
    int s0 = csr[e], s1 = csr[e + 1], s2 = csr[e + 2], s3 = csr[e + 3];
    int s4 = csr[e + 4], s5 = csr[e + 5], s6 = csr[e + 6], s7 = csr[e + 7];
    unsigned int p0 = *(const unsigned int*)(z + (size_t)s0 * H + lane * 2);
    unsigned int p1 = *(const unsigned int*)(z + (size_t)s1 * H + lane * 2);
    unsigned int p2 = *(const unsigned int*)(z + (size_t)s2 * H + lane * 2);
    unsigned int p3 = *(const unsigned int*)(z + (size_t)s3 * H + lane * 2);
    unsigned int p4 = *(const unsigned int*)(z + (size_t)s4 * H + lane * 2);
    unsigned int p5 = *(const unsigned int*)(z + (size_t)s5 * H + lane * 2);
    unsigned int p6 = *(const unsigned int*)(z + (size_t)s6 * H + lane * 2);
    unsigned int p7 = *(const unsigned int*)(z + (size_t)s7 * H + lane * 2);
    AGG_EDGE(p0) AGG_EDGE(p1) AGG_EDGE(p2) AGG_EDGE(p3)
    AGG_EDGE(p4) AGG_EDGE(p5) AGG_EDGE(p6) AGG_EDGE(p7)
  }
  for (; e + 4 <= end; e += 4) {
    int s0 = csr[e], s1 = csr[e + 1], s2 = csr[e + 2], s3 = csr[e + 3];
    unsigned int p0 = *(const unsigned int*)(z + (size_t)s0 * H + lane * 2);
    unsigned int p1 = *(const unsigned int*)(z + (size_t)s1 * H + lane * 2);
    unsigned int p2 = *(const unsigned int*)(z + (size_t)s2 * H + lane * 2);
    unsigned int p3 = *(const unsigned int*)(z + (size_t)s3 * H + lane * 2);
    AGG_EDGE(p0) AGG_EDGE(p1) AGG_EDGE(p2) AGG_EDGE(p3)
  }
  for (; e < end; e++) {
    int s = csr[e];
    unsigned int p = *(const unsigned int*)(z + (size_t)s * H + lane * 2);
    AGG_EDGE(p)
  }
  float a0 = (end > beg) ? sm0 / se0 : 0.f;
  float a1 = (end > beg) ? sm1 / se1 : 0.f;
  unsigned int pv = *(const unsigned int*)(z + (size_t)v * H + lane * 2);
  a0 += bf2f(pv & 0xffffu);
  a1 += bf2f(pv >> 16);
  unsigned int pack = (unsigned int)f2bf(a0) | ((unsigned int)f2bf(a1) << 16);
  *(unsigned int*)(out + (size_t)v * H + lane * 2) = pack;
}

// ------ fused MFMA MLP: h += (relu(LN(in@w1+b1)))@w2 + b2; z_next = relu(LN(h)) ------
// 64 nodes/block, 4 waves. bf16 MFMA 16x16x32, fp32 accum.
// GEMM1 A-fragments loaded DIRECT from global (tile is L1-resident for waves 2-4);
// s_mid XOR-swizzled; its first 16KB reused as z staging after GEMM2.
// LDS = 34KB -> 4 blocks/CU (was 51.2KB -> 3).
__global__ __launch_bounds__(256) void mlp_mfma_kernel(
    const unsigned short* __restrict__ inb,  // [N_PAD][128] bf16
    const unsigned short* __restrict__ w1t,  // [256][128] bf16 (B^T)
    const float* __restrict__ b1,
    const float* __restrict__ mg, const float* __restrict__ mb,
    const unsigned short* __restrict__ w2t,  // [128][256] bf16 (B^T)
    const float* __restrict__ b2,
    float* __restrict__ h,
    const float* __restrict__ g_next, const float* __restrict__ b_next,
    unsigned short* __restrict__ zout) {  // nullptr on last layer
  __shared__ __align__(16) unsigned short s_mid[64 * 256];  // 32KB
  __shared__ __align__(16) float s_sumv[64][4];
  __shared__ __align__(16) float s_sqv[64][4];
  int tid = threadIdx.x;
  int w = tid >> 6, l = tid & 63;
  int lr = l & 15, lg = l >> 4;
  int n0 = blockIdx.x * 64;

  // phase 1: GEMM1 (64x128)@(128x256). wave w -> cols [w*64, w*64+64)
  // A direct from global: a[mt] = inb[(n0+mt*16+lr)*H + ks*32 + lg*8 ..+8]
  f32x4 acc1[4][4];
#pragma unroll
  for (int mt = 0; mt < 4; mt++)
#pragma unroll
    for (int nt = 0; nt < 4; nt++) acc1[mt][nt] = (f32x4)(0.f);
#pragma unroll
  for (int ks = 0; ks < 4; ++ks) {
    int k = ks * 32 + lg * 8;
    short8 a[4], bfr[4];
#pragma unroll
    for (int mt = 0; mt < 4; mt++)
      a[mt] = *(const short8*)(inb + (size_t)(n0 + mt * 16 + lr) * H + k);
#pragma unroll
    for (int nt = 0; nt < 4; nt++) {
      int col = w * 64 + nt * 16 + lr;
      bfr[nt] = *(const short8*)(w1t + col * 128 + k);
    }
#pragma unroll
    for (int mt = 0; mt < 4; mt++)
#pragma unroll
      for (int nt = 0; nt < 4; nt++)
        acc1[mt][nt] = __builtin_amdgcn_mfma_f32_16x16x32_bf16(
            a[mt], bfr[nt], acc1[mt][nt], 0, 0, 0);
  }

  // bias
  float b1c[4];
#pragma unroll
  for (int nt = 0; nt < 4; nt++) b1c[nt] = b1[w * 64 + nt * 16 + lr];
#pragma unroll
  for (int mt = 0; mt < 4; mt++)
#pragma unroll
    for (int nt = 0; nt < 4; nt++)
#pragma unroll
      for (int j = 0; j < 4; j++) acc1[mt][nt][j] += b1c[nt];

  // in-register LN stats: per-row partial over this wave's 64 cols
#pragma unroll
  for (int mt = 0; mt < 4; mt++)
#pragma unroll
    for (int j = 0; j < 4; j++) {
      float s = 0.f, q = 0.f;
#pragma unroll
      for (int nt = 0; nt < 4; nt++) {
        float vv = acc1[mt][nt][j];
        s += vv; q += vv * vv;
      }
#pragma unroll
      for (int off = 1; off < 16; off <<= 1) {
        s += __shfl_xor(s, off, 64);
        q += __shfl_xor(q, off, 64);
      }
      if (lr == 0) {
        int row = mt * 16 + lg * 4 + j;
        s_sumv[row][w] = s;
        s_sqv[row][w] = q;
      }
    }
  __syncthreads();  // barrier 1

  // finalize mid-LN + relu + bf16 -> s_mid (swizzled)
  float mgc[4], mbc[4];
#pragma unroll
  for (int nt = 0; nt < 4; nt++) {
    int col = w * 64 + nt * 16 + lr;
    mgc[nt] = mg[col]; mbc[nt] = mb[col];
  }
#pragma unroll
  for (int mt = 0; mt < 4; mt++)
#pragma unroll
    for (int j = 0; j < 4; j++) {
      int row = mt * 16 + lg * 4 + j;
      float ssum = s_sumv[row][0] + s_sumv[row][1] + s_sumv[row][2] + s_sumv[row][3];
      float qsum = s_sqv[row][0] + s_sqv[row][1] + s_sqv[row][2] + s_sqv[row][3];
      float mu = ssum * (1.0f / H2);
      float var = qsum * (1.0f / H2) - mu * mu;
      float rstd = rsqrtf(fmaxf(var, 0.f) + LN_EPS);
#pragma unroll
      for (int nt = 0; nt < 4; nt++) {
        float vv = (acc1[mt][nt][j] - mu) * rstd * mgc[nt] + mbc[nt];
        vv = fmaxf(vv, 0.f);
        int col = w * 64 + nt * 16 + lr;
        s_mid[row * 256 + (col ^ ((row & 7) << 3))] = f2bf(vv);
      }
    }
  __syncthreads();  // barrier 2

  // phase 2: GEMM2 (64x256)@(256x128). wave w -> cols [w*32, w*32+32)
  f32x4 acc2[4][2];
#pragma unroll
  for (int mt = 0; mt < 4; mt++)
#pragma unroll
    for (int nt = 0; nt < 2; nt++) acc2[mt][nt] = (f32x4)(0.f);
#pragma unroll
  for (int ks = 0; ks < 8; ++ks) {
    int k = ks * 32 + lg * 8;
    short8 a[4], bfr[2];
#pragma unroll
    for (int mt = 0; mt < 4; mt++) {
      int row = mt * 16 + lr;
      a[mt] = *(const short8*)(&s_mid[row * 256 + (k ^ ((row & 7) << 3))]);
    }
#pragma unroll
    for (int nt = 0; nt < 2; nt++) {
      int col = w * 32 + nt * 16 + lr;
      bfr[nt] = *(const short8*)(w2t + col * 256 + k);
    }
#pragma unroll
    for (int mt = 0; mt < 4; mt++)
#pragma unroll
      for (int nt = 0; nt < 2; nt++)
        acc2[mt][nt] = __builtin_amdgcn_mfma_f32_16x16x32_bf16(
            a[mt], bfr[nt], acc2[mt][nt], 0, 0, 0);
  }

  // epilogue: hv = h_old + acc2 + b2 -> store h
  float b2c[2] = {b2[w * 32 + lr], b2[w * 32 + 16 + lr]};
#pragma unroll
  for (int mt = 0; mt < 4; mt++)
#pragma unroll
    for (int j = 0; j < 4; j++) {
      int n = n0 + mt * 16 + lg * 4 + j;
      bool valid = (n < N_NODES);
#pragma unroll
      for (int nt = 0; nt < 2; nt++) {
        int col = w * 32 + nt * 16 + lr;
        float hold = valid ? h[(size_t)n * H + col] : 0.f;
        float hv = hold + acc2[mt][nt][j] + b2c[nt];
        acc2[mt][nt][j] = hv;
        if (valid) h[(size_t)n * H + col] = hv;
      }
    }

  if (zout) {
    // next-layer LN stats (s_sumv safe to overwrite: all waves past barrier 2)
#pragma unroll
    for (int mt = 0; mt < 4; mt++)
#pragma unroll
      for (int j = 0; j < 4; j++) {
        float s = acc2[mt][0][j] + acc2[mt][1][j];
        float q = acc2[mt][0][j] * acc2[mt][0][j] + acc2[mt][1][j] * acc2[mt][1][j];
#pragma unroll
        for (int off = 1; off < 16; off <<= 1) {
          s += __shfl_xor(s, off, 64);
          q += __shfl_xor(q, off, 64);
        }
        if (lr == 0) {
          int row = mt * 16 + lg * 4 + j;
          s_sumv[row][w] = s;
          s_sqv[row][w] = q;
        }
      }
    __syncthreads();  // barrier 3: stats ready AND all GEMM2 s_mid reads done
    float gc[2] = {g_next[w * 32 + lr], g_next[w * 32 + 16 + lr]};
    float bc[2] = {b_next[w * 32 + lr], b_next[w * 32 + 16 + lr]};
#pragma unroll
    for (int mt = 0; mt < 4; mt++)
#pragma unroll
      for (int j = 0; j < 4; j++) {
        int row = mt * 16 + lg * 4 + j;
        float ssum = s_sumv[row][0] + s_sumv[row][1] + s_sumv[row][2] + s_sumv[row][3];
        float qsum = s_sqv[row][0] + s_sqv[row][1] + s_sqv[row][2] + s_sqv[row][3];
        float mu = ssum * (1.0f / H);
        float var = qsum * (1.0f / H) - mu * mu;
        float rstd = rsqrtf(fmaxf(var, 0.f) + LN_EPS);
#pragma unroll
        for (int nt = 0; nt < 2; nt++) {
          int col = w * 32 + nt * 16 + lr;
          float zz = fmaxf(gc[nt] * (acc2[mt][nt][j] - mu) * rstd + bc[nt], 0.f);
          // z staging in first 16KB of s_mid ([64][128] bf16, swizzled)
          s_mid[row * 128 + (col ^ ((row & 7) << 3))] = f2bf(zz);
        }
      }
    __syncthreads();  // barrier 4
    // coalesced 16B z store
#pragma unroll
    for (int it = 0; it < 4; ++it) {
      int id = it * 256 + tid;
      int row = id >> 4, c8 = (id & 15) * 8;
      int n = n0 + row;
      if (n < N_NODES) {
        uint4 val = *(const uint4*)(&s_mid[row * 128 + (c8 ^ ((row & 7) << 3))]);
        *(uint4*)(zout + (size_t)n * H + c8) = val;
      }
    }
  }
}

// ---------------- pooling (batch is sorted): 64-node chunks ----------------
__global__ __launch_bounds__(128) void pool_kernel(const float* __restrict__ h,
                                                   const int* __restrict__ batch,
                                                   float* __restrict__ pooled) {
  int c = threadIdx.x;  // 0..127
  int n0 = blockIdx.x * 64;
  int nend = n0 + 64;
  if (nend > N_NODES) nend = N_NODES;
  if (n0 >= N_NODES) return;
  float acc = 0.f;
  int cur = batch[n0];
  for (int n = n0; n < nend; n++) {
    int g = batch[n];
    if (g != cur) {
      atomicAdd(&pooled[cur * H + c], acc);
      acc = 0.f;
      cur = g;
    }
    acc += h[(size_t)n * H + c];
  }
  atomicAdd(&pooled[cur * H + c], acc);
}

// ---------------- classifier ----------------
__global__ __launch_bounds__(256) void cls_kernel(const float* __restrict__ pooled,
                                                  const float* __restrict__ cw,
                                                  const float* __restrict__ cb,
                                                  float* __restrict__ out) {
  int tid = threadIdx.x;
  int g = tid >> 2, c = tid & 3;
  float acc = cb[c];
  for (int k = 0; k < H; k++) acc += pooled[g * H + k] * cw[k * NCLS + c];
  out[g * NCLS + c] = acc;
}

extern "C" void kernel_launch(void* const* d_in, const int* in_sizes, int n_in,
                              void* d_out, int out_size, void* d_ws, size_t ws_size,
                              hipStream_t stream) {
  const float* x = (const float*)d_in[0];
  const int* edge_index = (const int*)d_in[1];
  const int* batch = (const int*)d_in[2];
  const float* enc_w = (const float*)d_in[3];
  const float* enc_b = (const float*)d_in[4];
  const float* ln_g = (const float*)d_in[5];
  const float* ln_b = (const float*)d_in[6];
  const float* t = (const float*)d_in[7];
  const float* w1 = (const float*)d_in[8];
  const float* b1 = (const float*)d_in[9];
  const float* mg = (const float*)d_in[10];
  const float* mb = (const float*)d_in[11];
  const float* w2 = (const float*)d_in[12];
  const float* b2 = (const float*)d_in[13];
  const float* cls_w = (const float*)d_in[14];
  const float* cls_b = (const float*)d_in[15];
  float* out = (float*)d_out;

  const int* src = edge_index;            // row 0
  const int* dst = edge_index + N_EDGES;  // row 1

  // workspace layout (all offsets 16B-aligned)
  char* ws = (char*)d_ws;
  float* hbuf = (float*)ws;                                  // N*H fp32
  unsigned short* zbuf = (unsigned short*)(hbuf + (size_t)N_NODES * H);
  unsigned short* obuf = zbuf + (size_t)N_NODES * H;         // N_PAD*H bf16
  unsigned short* w1t = obuf + (size_t)N_PAD * H;            // NL*H2*H bf16
  unsigned short* w2t = w1t + (size_t)NL * H * H2;           // NL*H*H2 bf16
  float* pooled = (float*)(w2t + (size_t)NL * H * H2);
  int* rowptr = (int*)(pooled + N_GRAPHS * H);
  int* cnt = rowptr + (N_NODES + 1);
  int* csr = cnt + N_NODES;

  hipMemsetAsync(cnt, 0, N_NODES * sizeof(int), stream);
  hipMemsetAsync(pooled, 0, N_GRAPHS * H * sizeof(float), stream);

  enc_ln_kernel<<<(N_NODES + 3) / 4, 256, 0, stream>>>(x, enc_w, enc_b, ln_g, ln_b,
                                                       hbuf, zbuf);
  wconv_kernel<<<(NL * H * H2 + 255) / 256, 256, 0, stream>>>(w1, w2, w1t, w2t);

  hist_kernel<<<(N_EDGES + 255) / 256, 256, 0, stream>>>(dst, cnt);
  scan_kernel<<<1, 1024, 0, stream>>>(cnt, rowptr);
  hipMemsetAsync(cnt, 0, N_NODES * sizeof(int), stream);  // reuse as cursor
  scatter_kernel<<<(N_EDGES + 255) / 256, 256, 0, stream>>>(src, dst, rowptr, cnt, csr);

  for (int l = 0; l < NL; l++) {
    agg_kernel<<<N_PAD / 4, 256, 0, stream>>>(zbuf, rowptr, csr, t + l, obuf);
    const float* gn = (l + 1 < NL) ? ln_g + (l + 1) * H : nullptr;
    const float* bn = (l + 1 < NL) ? ln_b + (l + 1) * H : nullptr;
    unsigned short* zo = (l + 1 < NL) ? zbuf : nullptr;
    mlp_mfma_kernel<<<N_PAD / 64, 256, 0, stream>>>(
        obuf, w1t + (size_t)l * H * H2, b1 + (size_t)l * H2, mg + (size_t)l * H2,
        mb + (size_t)l * H2, w2t + (size_t)l * H2 * H, b2 + (size_t)l * H, hbuf,
        gn, bn, zo);
  }

  pool_kernel<<<(N_NODES + 63) / 64, 128, 0, stream>>>(hbuf, batch, pooled);
  cls_kernel<<<1, 256, 0, stream>>>(pooled, cls_w, cls_b, out);
}